// Round 28
// baseline (200.328 us; speedup 1.0000x reference)
//
#include <hip/hip_runtime.h>

#define NPTS 4096
#define BATCH 4
#define KNN 20
#define ROT 116

__device__ __forceinline__ void vn_lrelu3(float p[3], const float d[3]) {
  float dot = p[0]*d[0] + p[1]*d[1] + p[2]*d[2];
  if (dot < 0.0f) {
    float dsq = d[0]*d[0] + d[1]*d[1] + d[2]*d[2];
    float r = dot / (dsq + 1e-6f);
    p[0] -= r*d[0]; p[1] -= r*d[1]; p[2] -= r*d[2];
  }
}

// ---------------- K1: fused KNN + edge + first VNT layer, TWO points/block.
//   (unchanged from round 19) ----------------
__global__ __launch_bounds__(256) void knn_edge2_kernel(const float* __restrict__ x,
                                                        const float* __restrict__ Wf,
                                                        const float* __restrict__ Wd,
                                                        float* __restrict__ h) {
  const int blk = blockIdx.x;                 // 0..8191
  const int rowA = blk << 1, rowB = rowA + 1;
  const int b = rowA >> 12;
  const int iA = rowA & (NPTS - 1), iB = rowB & (NPTS - 1);
  const float* __restrict__ xb = x + b * 3 * NPTS;
  const float cxA = xb[iA], cyA = xb[NPTS + iA], czA = xb[2 * NPTS + iA];
  const float cxB = xb[iB], cyB = xb[NPTS + iB], czB = xb[2 * NPTS + iB];
  const int t = threadIdx.x;
  const int j0 = t << 4;

  __shared__ unsigned int hist[2048];         // packed A|B<<16
  __shared__ unsigned int ldA_[384], ldB_[384];
  __shared__ int ljA_[384], ljB_[384];
  __shared__ unsigned int lcount;             // packed
  __shared__ int s_BA, s_BB;
  __shared__ unsigned int wtot[4];
  __shared__ int s_nbrA[KNN], s_nbrB[KNN];
  __shared__ float eA[KNN][3][3], eB[KNN][3][3];
  __shared__ float partA[2][64][3], partB[2][64][3];

  for (int k = t; k < 2048; k += 256) hist[k] = 0u;
  if (t == 0) lcount = 0u;
  __syncthreads();

  unsigned int dbA[16], dbB[16];
#pragma unroll
  for (int q = 0; q < 4; ++q) {
    const float4 px = *(const float4*)(xb + j0 + 4 * q);
    const float4 py = *(const float4*)(xb + NPTS + j0 + 4 * q);
    const float4 pz = *(const float4*)(xb + 2 * NPTS + j0 + 4 * q);
    float dx, dy, dz, dd;
    dx = px.x - cxA; dy = py.x - cyA; dz = pz.x - czA;
    dd = dx*dx + dy*dy + dz*dz; dbA[4*q+0] = __float_as_uint(dd);
    dx = px.y - cxA; dy = py.y - cyA; dz = pz.y - czA;
    dd = dx*dx + dy*dy + dz*dz; dbA[4*q+1] = __float_as_uint(dd);
    dx = px.z - cxA; dy = py.z - cyA; dz = pz.z - czA;
    dd = dx*dx + dy*dy + dz*dz; dbA[4*q+2] = __float_as_uint(dd);
    dx = px.w - cxA; dy = py.w - cyA; dz = pz.w - czA;
    dd = dx*dx + dy*dy + dz*dz; dbA[4*q+3] = __float_as_uint(dd);
    dx = px.x - cxB; dy = py.x - cyB; dz = pz.x - czB;
    dd = dx*dx + dy*dy + dz*dz; dbB[4*q+0] = __float_as_uint(dd);
    dx = px.y - cxB; dy = py.y - cyB; dz = pz.y - czB;
    dd = dx*dx + dy*dy + dz*dz; dbB[4*q+1] = __float_as_uint(dd);
    dx = px.z - cxB; dy = py.z - cyB; dz = pz.z - czB;
    dd = dx*dx + dy*dy + dz*dz; dbB[4*q+2] = __float_as_uint(dd);
    dx = px.w - cxB; dy = py.w - cyB; dz = pz.w - czB;
    dd = dx*dx + dy*dy + dz*dz; dbB[4*q+3] = __float_as_uint(dd);
  }
#pragma unroll
  for (int s = 0; s < 16; ++s) {
    atomicAdd(&hist[dbA[s] >> 20], 1u);
    atomicAdd(&hist[dbB[s] >> 20], 0x10000u);
  }
  __syncthreads();

  unsigned int v = 0;
#pragma unroll
  for (int s = 0; s < 8; ++s) v += hist[t * 8 + s];
  const unsigned int myps = v;
  const int lane = t & 63;
#pragma unroll
  for (int off = 1; off < 64; off <<= 1) {
    unsigned int n = (unsigned int)__shfl_up((int)v, off);
    if (lane >= off) v += n;
  }
  if (lane == 63) wtot[t >> 6] = v;
  __syncthreads();
  unsigned int woff = 0;
#pragma unroll
  for (int w = 0; w < 4; ++w) if (w < (t >> 6)) woff += wtot[w];
  const unsigned int cum_in = v + woff;
  const unsigned int cum_ex = cum_in - myps;
  {
    const int ci = (int)(cum_in & 0xffffu), ce = (int)(cum_ex & 0xffffu);
    if (ce < KNN && ci >= KNN) {
      int cum = ce, B = t * 8;
      for (int s = 0; s < 8; ++s) {
        const int hh = (int)(hist[t * 8 + s] & 0xffffu);
        if (cum + hh >= KNN) { B = t * 8 + s; break; }
        cum += hh;
      }
      s_BA = B;
    }
  }
  {
    const int ci = (int)(cum_in >> 16), ce = (int)(cum_ex >> 16);
    if (ce < KNN && ci >= KNN) {
      int cum = ce, B = t * 8;
      for (int s = 0; s < 8; ++s) {
        const int hh = (int)(hist[t * 8 + s] >> 16);
        if (cum + hh >= KNN) { B = t * 8 + s; break; }
        cum += hh;
      }
      s_BB = B;
    }
  }
  __syncthreads();
  const unsigned int BA = (unsigned int)s_BA, BB = (unsigned int)s_BB;
#pragma unroll
  for (int s = 0; s < 16; ++s) {
    if ((dbA[s] >> 20) <= BA) {
      unsigned int old = atomicAdd(&lcount, 1u);
      unsigned int pos = old & 0xffffu;
      if (pos < 384u) { ldA_[pos] = dbA[s]; ljA_[pos] = j0 + s; }
    }
    if ((dbB[s] >> 20) <= BB) {
      unsigned int old = atomicAdd(&lcount, 0x10000u);
      unsigned int pos = old >> 16;
      if (pos < 384u) { ldB_[pos] = dbB[s]; ljB_[pos] = j0 + s; }
    }
  }
  __syncthreads();
  const int nA = min((int)(lcount & 0xffffu), 384);
  const int nB = min((int)(lcount >> 16), 384);
  if (t < 128) {
    for (int idx = t; idx < nA; idx += 128) {
      const unsigned int kd = ldA_[idx]; const int kj = ljA_[idx];
      int rank = 0;
      for (int m = 0; m < nA; ++m) {
        const unsigned int md = ldA_[m];
        rank += (md < kd || (md == kd && ljA_[m] < kj)) ? 1 : 0;
      }
      if (rank < KNN) s_nbrA[rank] = kj;
    }
  } else {
    for (int idx = t - 128; idx < nB; idx += 128) {
      const unsigned int kd = ldB_[idx]; const int kj = ljB_[idx];
      int rank = 0;
      for (int m = 0; m < nB; ++m) {
        const unsigned int md = ldB_[m];
        rank += (md < kd || (md == kd && ljB_[m] < kj)) ? 1 : 0;
      }
      if (rank < KNN) s_nbrB[rank] = kj;
    }
  }
  __syncthreads();

  if (t < KNN) {
    const int j = s_nbrA[t];
    const float nx = xb[j], ny = xb[NPTS + j], nz = xb[2 * NPTS + j];
    eA[t][0][0] = nx - cxA; eA[t][0][1] = ny - cyA; eA[t][0][2] = nz - czA;
    eA[t][1][0] = cxA;      eA[t][1][1] = cyA;      eA[t][1][2] = czA;
    eA[t][2][0] = ny * czA - nz * cyA;
    eA[t][2][1] = nz * cxA - nx * czA;
    eA[t][2][2] = nx * cyA - ny * cxA;
  } else if (t >= 64 && t < 64 + KNN) {
    const int k = t - 64;
    const int j = s_nbrB[k];
    const float nx = xb[j], ny = xb[NPTS + j], nz = xb[2 * NPTS + j];
    eB[k][0][0] = nx - cxB; eB[k][0][1] = ny - cyB; eB[k][0][2] = nz - czB;
    eB[k][1][0] = cxB;      eB[k][1][1] = cyB;      eB[k][1][2] = czB;
    eB[k][2][0] = ny * czB - nz * cyB;
    eB[k][2][1] = nz * cxB - nx * czB;
    eB[k][2][2] = nx * cyB - ny * cxB;
  }
  __syncthreads();

  const int c = t & 63;
  const int half = t >> 7;
  const int kg = (t >> 6) & 1;
  float f0 = Wf[c * 3 + 0], f1 = Wf[c * 3 + 1], f2 = Wf[c * 3 + 2];
  const float s = 1.0f / (f0 + f1 + f2);
  f0 *= s; f1 *= s; f2 *= s;
  const float d0 = Wd[c * 3 + 0], d1 = Wd[c * 3 + 1], d2 = Wd[c * 3 + 2];
  float a0 = 0.f, a1 = 0.f, a2 = 0.f;
  const float (*e)[3][3] = (half == 0) ? eA : eB;
#pragma unroll
  for (int kk = 0; kk < 10; ++kk) {
    const int k = kg * 10 + kk;
    float pv[3], dv[3];
#pragma unroll
    for (int vv = 0; vv < 3; ++vv) {
      pv[vv] = f0 * e[k][0][vv] + f1 * e[k][1][vv] + f2 * e[k][2][vv];
      dv[vv] = d0 * e[k][0][vv] + d1 * e[k][1][vv] + d2 * e[k][2][vv];
    }
    vn_lrelu3(pv, dv);
    a0 += pv[0]; a1 += pv[1]; a2 += pv[2];
  }
  if (half == 0) { partA[kg][c][0] = a0; partA[kg][c][1] = a1; partA[kg][c][2] = a2; }
  else           { partB[kg][c][0] = a0; partB[kg][c][1] = a1; partB[kg][c][2] = a2; }
  __syncthreads();
  if (t < 64) {
    const float inv = 1.0f / KNN;
    float* hp = h + (size_t)rowA * 192 + t * 3;
#pragma unroll
    for (int vv = 0; vv < 3; ++vv)
      hp[vv] = (partA[0][t][vv] + partA[1][t][vv]) * inv;
  } else if (t < 128) {
    const int cc = t - 64;
    const float inv = 1.0f / KNN;
    float* hp = h + (size_t)rowB * 192 + cc * 3;
#pragma unroll
    for (int vv = 0; vv < 3; ++vv)
      hp[vv] = (partB[0][cc][vv] + partB[1][cc][vv]) * inv;
  }
}

// ------- K2: FUSED layer chain, 42.5 KB LDS, GRID 1024 (16 pts/block,
//   4 pts/wave = 2 passes x 2). Round-27 lesson: grid 512 capped blocks/CU
//   at 2 regardless of LDS; now 1024 blocks are available so a 128KB pool
//   admits 3 x 42.5KB -> 12 waves/CU. Weights padded to 65 (round-24). -------
__global__ __launch_bounds__(256) void chain_kernel(
    const float* __restrict__ hin,
    const float* __restrict__ Wc1f, const float* __restrict__ Wc1d,
    const float* __restrict__ Wc2f, const float* __restrict__ Wc2d,
    const float* __restrict__ Wtf,  const float* __restrict__ Wtd,
    const float* __restrict__ W1f,  const float* __restrict__ W1d,
    const float* __restrict__ W2f,  const float* __restrict__ W2d,
    float* __restrict__ rot_part, float* __restrict__ trans_part) {
  __shared__ float wfT[64][65], wdT[64][65];   // +1 pad (round-24 lesson)
  __shared__ float act[4][2][64][4];           // 8 KB: 2 pts/wave per pass
  __shared__ float tred[4][12][3];
  const int t = threadIdx.x, q = t >> 6, c = t & 63;
  const int pbase = (blockIdx.x * 4 + q) * 4;  // 4 points per wave

  float hx[4], hy[4], hz[4];                   // h, becomes hc in place
  float x2x[4], x2y[4], x2z[4];                // x2, later reused for y1
  float xcx[4], xcy[4], xcz[4];                // xc

  // ======== phase 1: Wc1 (VNT), h -> x2 ========
  for (int e = t; e < 4096; e += 256) { wfT[e&63][e>>6] = Wc1f[e]; wdT[e&63][e>>6] = Wc1d[e]; }
  __syncthreads();
  if (t < 64) {
    float s = 0.f;
    for (int i = 0; i < 64; ++i) s += wfT[i][t];
    s = 1.0f / s;
    for (int i = 0; i < 64; ++i) wfT[i][t] *= s;
  }
  __syncthreads();
#pragma unroll
  for (int pass = 0; pass < 2; ++pass) {
#pragma unroll
    for (int p = 0; p < 2; ++p) {
      const int pp = pass * 2 + p;
      const float* ip = hin + (size_t)(pbase + pp) * 192 + c * 3;
      hx[pp] = ip[0]; hy[pp] = ip[1]; hz[pp] = ip[2];
      *(float4*)act[q][p][c] = make_float4(hx[pp], hy[pp], hz[pp], 0.f);
    }
    __builtin_amdgcn_wave_barrier();
    float af[6], ad[6];
#pragma unroll
    for (int e2 = 0; e2 < 6; ++e2) { af[e2] = 0.f; ad[e2] = 0.f; }
    for (int i = 0; i < 64; ++i) {
      const float wfv = wfT[i][c], wdv = wdT[i][c];
#pragma unroll
      for (int p = 0; p < 2; ++p) {
        const float4 hv = *(const float4*)act[q][p][i];
        af[p*3+0] += wfv*hv.x; af[p*3+1] += wfv*hv.y; af[p*3+2] += wfv*hv.z;
        ad[p*3+0] += wdv*hv.x; ad[p*3+1] += wdv*hv.y; ad[p*3+2] += wdv*hv.z;
      }
    }
    __builtin_amdgcn_wave_barrier();
#pragma unroll
    for (int p = 0; p < 2; ++p) {
      const int pp = pass * 2 + p;
      float pf[3] = { af[p*3], af[p*3+1], af[p*3+2] };
      float pd[3] = { ad[p*3], ad[p*3+1], ad[p*3+2] };
      vn_lrelu3(pf, pd);
      x2x[pp] = pf[0]; x2y[pp] = pf[1]; x2z[pp] = pf[2];
    }
  }

  // ======== phase 2: Wc2 (VNT), x2 -> xc; hc = h - xc (regs) ========
  __syncthreads();
  for (int e = t; e < 4096; e += 256) { wfT[e&63][e>>6] = Wc2f[e]; wdT[e&63][e>>6] = Wc2d[e]; }
  __syncthreads();
  if (t < 64) {
    float s = 0.f;
    for (int i = 0; i < 64; ++i) s += wfT[i][t];
    s = 1.0f / s;
    for (int i = 0; i < 64; ++i) wfT[i][t] *= s;
  }
  __syncthreads();
#pragma unroll
  for (int pass = 0; pass < 2; ++pass) {
#pragma unroll
    for (int p = 0; p < 2; ++p) {
      const int pp = pass * 2 + p;
      *(float4*)act[q][p][c] = make_float4(x2x[pp], x2y[pp], x2z[pp], 0.f);
    }
    __builtin_amdgcn_wave_barrier();
    float af[6], ad[6];
#pragma unroll
    for (int e2 = 0; e2 < 6; ++e2) { af[e2] = 0.f; ad[e2] = 0.f; }
    for (int i = 0; i < 64; ++i) {
      const float wfv = wfT[i][c], wdv = wdT[i][c];
#pragma unroll
      for (int p = 0; p < 2; ++p) {
        const float4 hv = *(const float4*)act[q][p][i];
        af[p*3+0] += wfv*hv.x; af[p*3+1] += wfv*hv.y; af[p*3+2] += wfv*hv.z;
        ad[p*3+0] += wdv*hv.x; ad[p*3+1] += wdv*hv.y; ad[p*3+2] += wdv*hv.z;
      }
    }
    __builtin_amdgcn_wave_barrier();
#pragma unroll
    for (int p = 0; p < 2; ++p) {
      const int pp = pass * 2 + p;
      float pf[3] = { af[p*3], af[p*3+1], af[p*3+2] };
      float pd[3] = { ad[p*3], ad[p*3+1], ad[p*3+2] };
      vn_lrelu3(pf, pd);
      xcx[pp] = pf[0]; xcy[pp] = pf[1]; xcz[pp] = pf[2];
      hx[pp] -= pf[0]; hy[pp] -= pf[1]; hz[pp] -= pf[2];   // hc
    }
  }

  // ======== phase 3: Wt (VNT), xc -> trans acc (lane-quad split) ========
  __syncthreads();
  for (int e = t; e < 768; e += 256) { wfT[e&63][e>>6] = Wtf[e]; wdT[e&63][e>>6] = Wtd[e]; }
  __syncthreads();
  if (t < 12) {
    float s = 0.f;
    for (int i = 0; i < 64; ++i) s += wfT[i][t];
    s = 1.0f / s;
    for (int i = 0; i < 64; ++i) wfT[i][t] *= s;
  }
  __syncthreads();
  {
    const int cch = c >> 2, vv = c & 3;
    const bool actv = (cch < 12) && (vv < 3);
    float ta = 0.f;
#pragma unroll
    for (int pass = 0; pass < 2; ++pass) {
#pragma unroll
      for (int p = 0; p < 2; ++p) {
        const int pp = pass * 2 + p;
        *(float4*)act[q][p][c] = make_float4(xcx[pp], xcy[pp], xcz[pp], 0.f);
      }
      __builtin_amdgcn_wave_barrier();
#pragma unroll
      for (int p = 0; p < 2; ++p) {
        float pf = 0.f, pd = 0.f;
        if (actv) {
          for (int i = 0; i < 64; ++i) {
            const float a = act[q][p][i][vv];
            pf += wfT[i][cch] * a;
            pd += wdT[i][cch] * a;
          }
        }
        float pp2 = pf * pd, dd = pd * pd;
        pp2 += __shfl_xor(pp2, 1); pp2 += __shfl_xor(pp2, 2);
        dd  += __shfl_xor(dd, 1);  dd  += __shfl_xor(dd, 2);
        if (pp2 < 0.f) pf -= (pp2 / (dd + 1e-6f)) * pd;
        ta += pf;
      }
      __builtin_amdgcn_wave_barrier();
    }
    if (actv) { tred[q][cch][vv] = ta; }
  }

  // ======== phase 4: W1 (plain), hc -> y1 (reuse x2 regs) ========
  __syncthreads();
  for (int e = t; e < 4096; e += 256) { wfT[e&63][e>>6] = W1f[e]; wdT[e&63][e>>6] = W1d[e]; }
  __syncthreads();
#pragma unroll
  for (int pass = 0; pass < 2; ++pass) {
#pragma unroll
    for (int p = 0; p < 2; ++p) {
      const int pp = pass * 2 + p;
      *(float4*)act[q][p][c] = make_float4(hx[pp], hy[pp], hz[pp], 0.f);
    }
    __builtin_amdgcn_wave_barrier();
    float af[6], ad[6];
#pragma unroll
    for (int e2 = 0; e2 < 6; ++e2) { af[e2] = 0.f; ad[e2] = 0.f; }
    for (int i = 0; i < 64; ++i) {
      const float wfv = wfT[i][c], wdv = wdT[i][c];
#pragma unroll
      for (int p = 0; p < 2; ++p) {
        const float4 hv = *(const float4*)act[q][p][i];
        af[p*3+0] += wfv*hv.x; af[p*3+1] += wfv*hv.y; af[p*3+2] += wfv*hv.z;
        ad[p*3+0] += wdv*hv.x; ad[p*3+1] += wdv*hv.y; ad[p*3+2] += wdv*hv.z;
      }
    }
    __builtin_amdgcn_wave_barrier();
#pragma unroll
    for (int p = 0; p < 2; ++p) {
      const int pp = pass * 2 + p;
      float pf[3] = { af[p*3], af[p*3+1], af[p*3+2] };
      float pd[3] = { ad[p*3], ad[p*3+1], ad[p*3+2] };
      vn_lrelu3(pf, pd);
      x2x[pp] = pf[0]; x2y[pp] = pf[1]; x2z[pp] = pf[2];   // y1
    }
  }

  // ======== phase 5: W2 (plain), y1 -> h2; accumulate rot ========
  __syncthreads();
  for (int e = t; e < 4096; e += 256) { wfT[e&63][e>>6] = W2f[e]; wdT[e&63][e>>6] = W2d[e]; }
  __syncthreads();
  float r0 = 0.f, r1 = 0.f, r2 = 0.f;
#pragma unroll
  for (int pass = 0; pass < 2; ++pass) {
#pragma unroll
    for (int p = 0; p < 2; ++p) {
      const int pp = pass * 2 + p;
      *(float4*)act[q][p][c] = make_float4(x2x[pp], x2y[pp], x2z[pp], 0.f);
    }
    __builtin_amdgcn_wave_barrier();
    float af[6], ad[6];
#pragma unroll
    for (int e2 = 0; e2 < 6; ++e2) { af[e2] = 0.f; ad[e2] = 0.f; }
    for (int i = 0; i < 64; ++i) {
      const float wfv = wfT[i][c], wdv = wdT[i][c];
#pragma unroll
      for (int p = 0; p < 2; ++p) {
        const float4 hv = *(const float4*)act[q][p][i];
        af[p*3+0] += wfv*hv.x; af[p*3+1] += wfv*hv.y; af[p*3+2] += wfv*hv.z;
        ad[p*3+0] += wdv*hv.x; ad[p*3+1] += wdv*hv.y; ad[p*3+2] += wdv*hv.z;
      }
    }
    __builtin_amdgcn_wave_barrier();
#pragma unroll
    for (int p = 0; p < 2; ++p) {
      float pf[3] = { af[p*3], af[p*3+1], af[p*3+2] };
      float pd[3] = { ad[p*3], ad[p*3+1], ad[p*3+2] };
      vn_lrelu3(pf, pd);
      r0 += pf[0]; r1 += pf[1]; r2 += pf[2];
    }
    __builtin_amdgcn_wave_barrier();
  }

  // ======== epilogue: block-reduce rot + trans partials ========
  __syncthreads();
  *(float4*)act[q][0][c] = make_float4(r0, r1, r2, 0.f);
  __syncthreads();
  if (t < 192) {
    const int cc = t / 3, vv = t - cc * 3;
    rot_part[blockIdx.x * 192 + t] =
        act[0][0][cc][vv] + act[1][0][cc][vv] + act[2][0][cc][vv] + act[3][0][cc][vv];
  } else if (t >= 192 && t < 228) {
    const int tt = t - 192;
    const int cc = tt / 3, vv = tt - cc * 3;
    trans_part[blockIdx.x * 36 + tt] =
        tred[0][cc][vv] + tred[1][cc][vv] + tred[2][cc][vv] + tred[3][cc][vv];
  }
}

// ------- K3: reduce partials (256 blocks/batch), W3 @ mean(h2), concat. -------
__global__ __launch_bounds__(384) void finalize_kernel(const float* __restrict__ rot_part,
                                                       const float* __restrict__ trans_part,
                                                       const float* __restrict__ W3,
                                                       float* __restrict__ out) {
  const int b = blockIdx.x;
  const int t = threadIdx.x;
  __shared__ float hsum[64][3];
  if (t < 192) {
    float s = 0.f;
    for (int blk = 0; blk < 256; ++blk)
      s += rot_part[(b * 256 + blk) * 192 + t];
    hsum[t / 3][t % 3] = s * (1.0f / NPTS);
  } else if (t < 228) {
    const int tt = t - 192;
    float s = 0.f;
    for (int blk = 0; blk < 256; ++blk)
      s += trans_part[(b * 256 + blk) * 36 + tt];
    out[b * 384 + 348 + tt] = s * (1.0f / NPTS);
  }
  __syncthreads();
  if (t < 348) {
    const int ch = t / 3, v = t - ch * 3;
    float s = 0.f;
    for (int i = 0; i < 64; ++i) s += W3[ch * 64 + i] * hsum[i][v];
    out[b * 384 + t] = s;
  }
}

extern "C" void kernel_launch(void* const* d_in, const int* in_sizes, int n_in,
                              void* d_out, int out_size, void* d_ws, size_t ws_size,
                              hipStream_t stream) {
  (void)in_sizes; (void)n_in; (void)out_size; (void)ws_size;
  const float* x     = (const float*)d_in[0];
  const float* Wposf = (const float*)d_in[1];
  const float* Wposd = (const float*)d_in[2];
  const float* Wc1f  = (const float*)d_in[3];
  const float* Wc1d  = (const float*)d_in[4];
  const float* Wc2f  = (const float*)d_in[5];
  const float* Wc2d  = (const float*)d_in[6];
  const float* Wtf   = (const float*)d_in[7];
  const float* Wtd   = (const float*)d_in[8];
  const float* W1f   = (const float*)d_in[9];
  const float* W1d   = (const float*)d_in[10];
  const float* W2f   = (const float*)d_in[11];
  const float* W2d   = (const float*)d_in[12];
  const float* W3    = (const float*)d_in[13];
  float* out = (float*)d_out;

  char* ws = (char*)d_ws;
  float* P          = (float*)(ws + 1310720);            // h (from knn_edge2), 12.58 MB
  float* rot_part   = (float*)(ws + 13893632);           // 1024*192*4 = 786,432 B
  float* trans_part = (float*)(ws + 14680064);           // 1024*36*4  = 147,456 B

  knn_edge2_kernel<<<BATCH * NPTS / 2, 256, 0, stream>>>(x, Wposf, Wposd, P);  // x -> h
  chain_kernel<<<1024, 256, 0, stream>>>(P, Wc1f, Wc1d, Wc2f, Wc2d, Wtf, Wtd,
                                         W1f, W1d, W2f, W2d, rot_part, trans_part);
  finalize_kernel<<<BATCH, 384, 0, stream>>>(rot_part, trans_part, W3, out);
}

// Round 29
// 183.399 us; speedup vs baseline: 1.0923x; 1.0923x over previous
//
#include <hip/hip_runtime.h>

#define NPTS 4096
#define BATCH 4
#define KNN 20
#define ROT 116

__device__ __forceinline__ void vn_lrelu3(float p[3], const float d[3]) {
  float dot = p[0]*d[0] + p[1]*d[1] + p[2]*d[2];
  if (dot < 0.0f) {
    float dsq = d[0]*d[0] + d[1]*d[1] + d[2]*d[2];
    float r = dot / (dsq + 1e-6f);
    p[0] -= r*d[0]; p[1] -= r*d[1]; p[2] -= r*d[2];
  }
}

// ---------------- K1: fused KNN + edge + first VNT layer, TWO points/block. ----------------
__global__ __launch_bounds__(256) void knn_edge2_kernel(const float* __restrict__ x,
                                                        const float* __restrict__ Wf,
                                                        const float* __restrict__ Wd,
                                                        float* __restrict__ h) {
  const int blk = blockIdx.x;                 // 0..8191
  const int rowA = blk << 1, rowB = rowA + 1;
  const int b = rowA >> 12;
  const int iA = rowA & (NPTS - 1), iB = rowB & (NPTS - 1);
  const float* __restrict__ xb = x + b * 3 * NPTS;
  const float cxA = xb[iA], cyA = xb[NPTS + iA], czA = xb[2 * NPTS + iA];
  const float cxB = xb[iB], cyB = xb[NPTS + iB], czB = xb[2 * NPTS + iB];
  const int t = threadIdx.x;
  const int j0 = t << 4;

  __shared__ unsigned int hist[2048];         // packed A|B<<16
  __shared__ unsigned int ldA_[384], ldB_[384];
  __shared__ int ljA_[384], ljB_[384];
  __shared__ unsigned int lcount;             // packed
  __shared__ int s_BA, s_BB;
  __shared__ unsigned int wtot[4];
  __shared__ int s_nbrA[KNN], s_nbrB[KNN];
  __shared__ float eA[KNN][3][3], eB[KNN][3][3];
  __shared__ float partA[2][64][3], partB[2][64][3];

  for (int k = t; k < 2048; k += 256) hist[k] = 0u;
  if (t == 0) lcount = 0u;
  __syncthreads();

  unsigned int dbA[16], dbB[16];
#pragma unroll
  for (int q = 0; q < 4; ++q) {
    const float4 px = *(const float4*)(xb + j0 + 4 * q);
    const float4 py = *(const float4*)(xb + NPTS + j0 + 4 * q);
    const float4 pz = *(const float4*)(xb + 2 * NPTS + j0 + 4 * q);
    float dx, dy, dz, dd;
    dx = px.x - cxA; dy = py.x - cyA; dz = pz.x - czA;
    dd = dx*dx + dy*dy + dz*dz; dbA[4*q+0] = __float_as_uint(dd);
    dx = px.y - cxA; dy = py.y - cyA; dz = pz.y - czA;
    dd = dx*dx + dy*dy + dz*dz; dbA[4*q+1] = __float_as_uint(dd);
    dx = px.z - cxA; dy = py.z - cyA; dz = pz.z - czA;
    dd = dx*dx + dy*dy + dz*dz; dbA[4*q+2] = __float_as_uint(dd);
    dx = px.w - cxA; dy = py.w - cyA; dz = pz.w - czA;
    dd = dx*dx + dy*dy + dz*dz; dbA[4*q+3] = __float_as_uint(dd);
    dx = px.x - cxB; dy = py.x - cyB; dz = pz.x - czB;
    dd = dx*dx + dy*dy + dz*dz; dbB[4*q+0] = __float_as_uint(dd);
    dx = px.y - cxB; dy = py.y - cyB; dz = pz.y - czB;
    dd = dx*dx + dy*dy + dz*dz; dbB[4*q+1] = __float_as_uint(dd);
    dx = px.z - cxB; dy = py.z - cyB; dz = pz.z - czB;
    dd = dx*dx + dy*dy + dz*dz; dbB[4*q+2] = __float_as_uint(dd);
    dx = px.w - cxB; dy = py.w - cyB; dz = pz.w - czB;
    dd = dx*dx + dy*dy + dz*dz; dbB[4*q+3] = __float_as_uint(dd);
  }
#pragma unroll
  for (int s = 0; s < 16; ++s) {
    atomicAdd(&hist[dbA[s] >> 20], 1u);
    atomicAdd(&hist[dbB[s] >> 20], 0x10000u);
  }
  __syncthreads();

  unsigned int v = 0;
#pragma unroll
  for (int s = 0; s < 8; ++s) v += hist[t * 8 + s];
  const unsigned int myps = v;
  const int lane = t & 63;
#pragma unroll
  for (int off = 1; off < 64; off <<= 1) {
    unsigned int n = (unsigned int)__shfl_up((int)v, off);
    if (lane >= off) v += n;
  }
  if (lane == 63) wtot[t >> 6] = v;
  __syncthreads();
  unsigned int woff = 0;
#pragma unroll
  for (int w = 0; w < 4; ++w) if (w < (t >> 6)) woff += wtot[w];
  const unsigned int cum_in = v + woff;
  const unsigned int cum_ex = cum_in - myps;
  {
    const int ci = (int)(cum_in & 0xffffu), ce = (int)(cum_ex & 0xffffu);
    if (ce < KNN && ci >= KNN) {
      int cum = ce, B = t * 8;
      for (int s = 0; s < 8; ++s) {
        const int hh = (int)(hist[t * 8 + s] & 0xffffu);
        if (cum + hh >= KNN) { B = t * 8 + s; break; }
        cum += hh;
      }
      s_BA = B;
    }
  }
  {
    const int ci = (int)(cum_in >> 16), ce = (int)(cum_ex >> 16);
    if (ce < KNN && ci >= KNN) {
      int cum = ce, B = t * 8;
      for (int s = 0; s < 8; ++s) {
        const int hh = (int)(hist[t * 8 + s] >> 16);
        if (cum + hh >= KNN) { B = t * 8 + s; break; }
        cum += hh;
      }
      s_BB = B;
    }
  }
  __syncthreads();
  const unsigned int BA = (unsigned int)s_BA, BB = (unsigned int)s_BB;
#pragma unroll
  for (int s = 0; s < 16; ++s) {
    if ((dbA[s] >> 20) <= BA) {
      unsigned int old = atomicAdd(&lcount, 1u);
      unsigned int pos = old & 0xffffu;
      if (pos < 384u) { ldA_[pos] = dbA[s]; ljA_[pos] = j0 + s; }
    }
    if ((dbB[s] >> 20) <= BB) {
      unsigned int old = atomicAdd(&lcount, 0x10000u);
      unsigned int pos = old >> 16;
      if (pos < 384u) { ldB_[pos] = dbB[s]; ljB_[pos] = j0 + s; }
    }
  }
  __syncthreads();
  const int nA = min((int)(lcount & 0xffffu), 384);
  const int nB = min((int)(lcount >> 16), 384);
  if (t < 128) {
    for (int idx = t; idx < nA; idx += 128) {
      const unsigned int kd = ldA_[idx]; const int kj = ljA_[idx];
      int rank = 0;
      for (int m = 0; m < nA; ++m) {
        const unsigned int md = ldA_[m];
        rank += (md < kd || (md == kd && ljA_[m] < kj)) ? 1 : 0;
      }
      if (rank < KNN) s_nbrA[rank] = kj;
    }
  } else {
    for (int idx = t - 128; idx < nB; idx += 128) {
      const unsigned int kd = ldB_[idx]; const int kj = ljB_[idx];
      int rank = 0;
      for (int m = 0; m < nB; ++m) {
        const unsigned int md = ldB_[m];
        rank += (md < kd || (md == kd && ljB_[m] < kj)) ? 1 : 0;
      }
      if (rank < KNN) s_nbrB[rank] = kj;
    }
  }
  __syncthreads();

  if (t < KNN) {
    const int j = s_nbrA[t];
    const float nx = xb[j], ny = xb[NPTS + j], nz = xb[2 * NPTS + j];
    eA[t][0][0] = nx - cxA; eA[t][0][1] = ny - cyA; eA[t][0][2] = nz - czA;
    eA[t][1][0] = cxA;      eA[t][1][1] = cyA;      eA[t][1][2] = czA;
    eA[t][2][0] = ny * czA - nz * cyA;
    eA[t][2][1] = nz * cxA - nx * czA;
    eA[t][2][2] = nx * cyA - ny * cxA;
  } else if (t >= 64 && t < 64 + KNN) {
    const int k = t - 64;
    const int j = s_nbrB[k];
    const float nx = xb[j], ny = xb[NPTS + j], nz = xb[2 * NPTS + j];
    eB[k][0][0] = nx - cxB; eB[k][0][1] = ny - cyB; eB[k][0][2] = nz - czB;
    eB[k][1][0] = cxB;      eB[k][1][1] = cyB;      eB[k][1][2] = czB;
    eB[k][2][0] = ny * czB - nz * cyB;
    eB[k][2][1] = nz * cxB - nx * czB;
    eB[k][2][2] = nx * cyB - ny * cxB;
  }
  __syncthreads();

  const int c = t & 63;
  const int half = t >> 7;
  const int kg = (t >> 6) & 1;
  float f0 = Wf[c * 3 + 0], f1 = Wf[c * 3 + 1], f2 = Wf[c * 3 + 2];
  const float s = 1.0f / (f0 + f1 + f2);
  f0 *= s; f1 *= s; f2 *= s;
  const float d0 = Wd[c * 3 + 0], d1 = Wd[c * 3 + 1], d2 = Wd[c * 3 + 2];
  float a0 = 0.f, a1 = 0.f, a2 = 0.f;
  const float (*e)[3][3] = (half == 0) ? eA : eB;
#pragma unroll
  for (int kk = 0; kk < 10; ++kk) {
    const int k = kg * 10 + kk;
    float pv[3], dv[3];
#pragma unroll
    for (int vv = 0; vv < 3; ++vv) {
      pv[vv] = f0 * e[k][0][vv] + f1 * e[k][1][vv] + f2 * e[k][2][vv];
      dv[vv] = d0 * e[k][0][vv] + d1 * e[k][1][vv] + d2 * e[k][2][vv];
    }
    vn_lrelu3(pv, dv);
    a0 += pv[0]; a1 += pv[1]; a2 += pv[2];
  }
  if (half == 0) { partA[kg][c][0] = a0; partA[kg][c][1] = a1; partA[kg][c][2] = a2; }
  else           { partB[kg][c][0] = a0; partB[kg][c][1] = a1; partB[kg][c][2] = a2; }
  __syncthreads();
  if (t < 64) {
    const float inv = 1.0f / KNN;
    float* hp = h + (size_t)rowA * 192 + t * 3;
#pragma unroll
    for (int vv = 0; vv < 3; ++vv)
      hp[vv] = (partA[0][t][vv] + partA[1][t][vv]) * inv;
  } else if (t < 128) {
    const int cc = t - 64;
    const float inv = 1.0f / KNN;
    float* hp = h + (size_t)rowB * 192 + cc * 3;
#pragma unroll
    for (int vv = 0; vv < 3; ++vv)
      hp[vv] = (partB[0][cc][vv] + partB[1][cc][vv]) * inv;
  }
}

// ------- K2: FUSED layer chain (round-20 measured-best config):
//   256 thr, grid 512, 32 pts/block (8 pts/wave, 2 passes x 4),
//   weights stride-65, act[4][4][64][4]. -------
__global__ __launch_bounds__(256) void chain_kernel(
    const float* __restrict__ hin,
    const float* __restrict__ Wc1f, const float* __restrict__ Wc1d,
    const float* __restrict__ Wc2f, const float* __restrict__ Wc2d,
    const float* __restrict__ Wtf,  const float* __restrict__ Wtd,
    const float* __restrict__ W1f,  const float* __restrict__ W1d,
    const float* __restrict__ W2f,  const float* __restrict__ W2d,
    float* __restrict__ rot_part, float* __restrict__ trans_part) {
  __shared__ float wfT[64][65], wdT[64][65];   // reused across all phases
  __shared__ float act[4][4][64][4];
  __shared__ float tred[4][12][3];
  const int t = threadIdx.x, q = t >> 6, c = t & 63;
  const int pbase = (blockIdx.x * 4 + q) * 8;

  float hx[8], hy[8], hz[8];                   // h, becomes hc in place
  float x2x[8], x2y[8], x2z[8];                // x2, later reused for y1
  float xcx[8], xcy[8], xcz[8];                // xc

  // ======== phase 1: Wc1 (VNT), h -> x2 ========
  for (int e = t; e < 4096; e += 256) { wfT[e&63][e>>6] = Wc1f[e]; wdT[e&63][e>>6] = Wc1d[e]; }
  __syncthreads();
  if (t < 64) {
    float s = 0.f;
    for (int i = 0; i < 64; ++i) s += wfT[i][t];
    s = 1.0f / s;
    for (int i = 0; i < 64; ++i) wfT[i][t] *= s;
  }
  __syncthreads();
#pragma unroll
  for (int pass = 0; pass < 2; ++pass) {
#pragma unroll
    for (int p = 0; p < 4; ++p) {
      const int pp = pass * 4 + p;
      const float* ip = hin + (size_t)(pbase + pp) * 192 + c * 3;
      hx[pp] = ip[0]; hy[pp] = ip[1]; hz[pp] = ip[2];
      *(float4*)act[q][p][c] = make_float4(hx[pp], hy[pp], hz[pp], 0.f);
    }
    __builtin_amdgcn_wave_barrier();
    float af[12], ad[12];
#pragma unroll
    for (int e2 = 0; e2 < 12; ++e2) { af[e2] = 0.f; ad[e2] = 0.f; }
    for (int i = 0; i < 64; ++i) {
      const float wfv = wfT[i][c], wdv = wdT[i][c];
#pragma unroll
      for (int p = 0; p < 4; ++p) {
        const float4 hv = *(const float4*)act[q][p][i];
        af[p*3+0] += wfv*hv.x; af[p*3+1] += wfv*hv.y; af[p*3+2] += wfv*hv.z;
        ad[p*3+0] += wdv*hv.x; ad[p*3+1] += wdv*hv.y; ad[p*3+2] += wdv*hv.z;
      }
    }
    __builtin_amdgcn_wave_barrier();
#pragma unroll
    for (int p = 0; p < 4; ++p) {
      const int pp = pass * 4 + p;
      float pf[3] = { af[p*3], af[p*3+1], af[p*3+2] };
      float pd[3] = { ad[p*3], ad[p*3+1], ad[p*3+2] };
      vn_lrelu3(pf, pd);
      x2x[pp] = pf[0]; x2y[pp] = pf[1]; x2z[pp] = pf[2];
    }
  }

  // ======== phase 2: Wc2 (VNT), x2 -> xc; hc = h - xc (regs) ========
  __syncthreads();
  for (int e = t; e < 4096; e += 256) { wfT[e&63][e>>6] = Wc2f[e]; wdT[e&63][e>>6] = Wc2d[e]; }
  __syncthreads();
  if (t < 64) {
    float s = 0.f;
    for (int i = 0; i < 64; ++i) s += wfT[i][t];
    s = 1.0f / s;
    for (int i = 0; i < 64; ++i) wfT[i][t] *= s;
  }
  __syncthreads();
#pragma unroll
  for (int pass = 0; pass < 2; ++pass) {
#pragma unroll
    for (int p = 0; p < 4; ++p) {
      const int pp = pass * 4 + p;
      *(float4*)act[q][p][c] = make_float4(x2x[pp], x2y[pp], x2z[pp], 0.f);
    }
    __builtin_amdgcn_wave_barrier();
    float af[12], ad[12];
#pragma unroll
    for (int e2 = 0; e2 < 12; ++e2) { af[e2] = 0.f; ad[e2] = 0.f; }
    for (int i = 0; i < 64; ++i) {
      const float wfv = wfT[i][c], wdv = wdT[i][c];
#pragma unroll
      for (int p = 0; p < 4; ++p) {
        const float4 hv = *(const float4*)act[q][p][i];
        af[p*3+0] += wfv*hv.x; af[p*3+1] += wfv*hv.y; af[p*3+2] += wfv*hv.z;
        ad[p*3+0] += wdv*hv.x; ad[p*3+1] += wdv*hv.y; ad[p*3+2] += wdv*hv.z;
      }
    }
    __builtin_amdgcn_wave_barrier();
#pragma unroll
    for (int p = 0; p < 4; ++p) {
      const int pp = pass * 4 + p;
      float pf[3] = { af[p*3], af[p*3+1], af[p*3+2] };
      float pd[3] = { ad[p*3], ad[p*3+1], ad[p*3+2] };
      vn_lrelu3(pf, pd);
      xcx[pp] = pf[0]; xcy[pp] = pf[1]; xcz[pp] = pf[2];
      hx[pp] -= pf[0]; hy[pp] -= pf[1]; hz[pp] -= pf[2];   // hc
    }
  }

  // ======== phase 3: Wt (VNT, 12 rows), xc -> trans acc ========
  __syncthreads();
  for (int e = t; e < 768; e += 256) { wfT[e&63][e>>6] = Wtf[e]; wdT[e&63][e>>6] = Wtd[e]; }
  __syncthreads();
  if (t < 12) {
    float s = 0.f;
    for (int i = 0; i < 64; ++i) s += wfT[i][t];
    s = 1.0f / s;
    for (int i = 0; i < 64; ++i) wfT[i][t] *= s;
  }
  __syncthreads();
  {
    const int cch = c >> 2, vv = c & 3;        // lane-quad split
    const bool actv = (cch < 12) && (vv < 3);
    float ta = 0.f;
#pragma unroll
    for (int pass = 0; pass < 2; ++pass) {
#pragma unroll
      for (int p = 0; p < 4; ++p) {
        const int pp = pass * 4 + p;
        *(float4*)act[q][p][c] = make_float4(xcx[pp], xcy[pp], xcz[pp], 0.f);
      }
      __builtin_amdgcn_wave_barrier();
#pragma unroll
      for (int p = 0; p < 4; ++p) {
        float pf = 0.f, pd = 0.f;
        if (actv) {
          for (int i = 0; i < 64; ++i) {
            const float a = act[q][p][i][vv];
            pf += wfT[i][cch] * a;
            pd += wdT[i][cch] * a;
          }
        }
        float pp2 = pf * pd, dd = pd * pd;     // inactive lanes contribute 0
        pp2 += __shfl_xor(pp2, 1); pp2 += __shfl_xor(pp2, 2);
        dd  += __shfl_xor(dd, 1);  dd  += __shfl_xor(dd, 2);
        if (pp2 < 0.f) pf -= (pp2 / (dd + 1e-6f)) * pd;
        ta += pf;
      }
      __builtin_amdgcn_wave_barrier();
    }
    if (actv) { tred[q][cch][vv] = ta; }
  }

  // ======== phase 4: W1 (plain), hc -> y1 (reuse x2 regs) ========
  __syncthreads();
  for (int e = t; e < 4096; e += 256) { wfT[e&63][e>>6] = W1f[e]; wdT[e&63][e>>6] = W1d[e]; }
  __syncthreads();
#pragma unroll
  for (int pass = 0; pass < 2; ++pass) {
#pragma unroll
    for (int p = 0; p < 4; ++p) {
      const int pp = pass * 4 + p;
      *(float4*)act[q][p][c] = make_float4(hx[pp], hy[pp], hz[pp], 0.f);
    }
    __builtin_amdgcn_wave_barrier();
    float af[12], ad[12];
#pragma unroll
    for (int e2 = 0; e2 < 12; ++e2) { af[e2] = 0.f; ad[e2] = 0.f; }
    for (int i = 0; i < 64; ++i) {
      const float wfv = wfT[i][c], wdv = wdT[i][c];
#pragma unroll
      for (int p = 0; p < 4; ++p) {
        const float4 hv = *(const float4*)act[q][p][i];
        af[p*3+0] += wfv*hv.x; af[p*3+1] += wfv*hv.y; af[p*3+2] += wfv*hv.z;
        ad[p*3+0] += wdv*hv.x; ad[p*3+1] += wdv*hv.y; ad[p*3+2] += wdv*hv.z;
      }
    }
    __builtin_amdgcn_wave_barrier();
#pragma unroll
    for (int p = 0; p < 4; ++p) {
      const int pp = pass * 4 + p;
      float pf[3] = { af[p*3], af[p*3+1], af[p*3+2] };
      float pd[3] = { ad[p*3], ad[p*3+1], ad[p*3+2] };
      vn_lrelu3(pf, pd);
      x2x[pp] = pf[0]; x2y[pp] = pf[1]; x2z[pp] = pf[2];   // y1
    }
  }

  // ======== phase 5: W2 (plain), y1 -> h2; accumulate rot ========
  __syncthreads();
  for (int e = t; e < 4096; e += 256) { wfT[e&63][e>>6] = W2f[e]; wdT[e&63][e>>6] = W2d[e]; }
  __syncthreads();
  float r0 = 0.f, r1 = 0.f, r2 = 0.f;
#pragma unroll
  for (int pass = 0; pass < 2; ++pass) {
#pragma unroll
    for (int p = 0; p < 4; ++p) {
      const int pp = pass * 4 + p;
      *(float4*)act[q][p][c] = make_float4(x2x[pp], x2y[pp], x2z[pp], 0.f);
    }
    __builtin_amdgcn_wave_barrier();
    float af[12], ad[12];
#pragma unroll
    for (int e2 = 0; e2 < 12; ++e2) { af[e2] = 0.f; ad[e2] = 0.f; }
    for (int i = 0; i < 64; ++i) {
      const float wfv = wfT[i][c], wdv = wdT[i][c];
#pragma unroll
      for (int p = 0; p < 4; ++p) {
        const float4 hv = *(const float4*)act[q][p][i];
        af[p*3+0] += wfv*hv.x; af[p*3+1] += wfv*hv.y; af[p*3+2] += wfv*hv.z;
        ad[p*3+0] += wdv*hv.x; ad[p*3+1] += wdv*hv.y; ad[p*3+2] += wdv*hv.z;
      }
    }
    __builtin_amdgcn_wave_barrier();
#pragma unroll
    for (int p = 0; p < 4; ++p) {
      float pf[3] = { af[p*3], af[p*3+1], af[p*3+2] };
      float pd[3] = { ad[p*3], ad[p*3+1], ad[p*3+2] };
      vn_lrelu3(pf, pd);
      r0 += pf[0]; r1 += pf[1]; r2 += pf[2];
    }
    __builtin_amdgcn_wave_barrier();
  }

  // ======== epilogue: block-reduce rot + trans partials ========
  *(float4*)act[q][0][c] = make_float4(r0, r1, r2, 0.f);
  __syncthreads();
  if (t < 192) {
    const int cc = t / 3, vv = t - cc * 3;
    rot_part[blockIdx.x * 192 + t] =
        act[0][0][cc][vv] + act[1][0][cc][vv] + act[2][0][cc][vv] + act[3][0][cc][vv];
  } else if (t >= 192 && t < 228) {
    const int tt = t - 192;
    const int cc = tt / 3, vv = tt - cc * 3;
    trans_part[blockIdx.x * 36 + tt] =
        tred[0][cc][vv] + tred[1][cc][vv] + tred[2][cc][vv] + tred[3][cc][vv];
  }
}

// ------- K3: reduce partials, W3 @ mean(h2), concat. -------
__global__ __launch_bounds__(384) void finalize_kernel(const float* __restrict__ rot_part,
                                                       const float* __restrict__ trans_part,
                                                       const float* __restrict__ W3,
                                                       float* __restrict__ out) {
  const int b = blockIdx.x;
  const int t = threadIdx.x;
  __shared__ float hsum[64][3];
  if (t < 192) {
    float s = 0.f;
    for (int blk = 0; blk < 128; ++blk)
      s += rot_part[(b * 128 + blk) * 192 + t];
    hsum[t / 3][t % 3] = s * (1.0f / NPTS);
  } else if (t < 228) {
    const int tt = t - 192;
    float s = 0.f;
    for (int blk = 0; blk < 128; ++blk)
      s += trans_part[(b * 128 + blk) * 36 + tt];
    out[b * 384 + 348 + tt] = s * (1.0f / NPTS);
  }
  __syncthreads();
  if (t < 348) {
    const int ch = t / 3, v = t - ch * 3;
    float s = 0.f;
    for (int i = 0; i < 64; ++i) s += W3[ch * 64 + i] * hsum[i][v];
    out[b * 384 + t] = s;
  }
}

extern "C" void kernel_launch(void* const* d_in, const int* in_sizes, int n_in,
                              void* d_out, int out_size, void* d_ws, size_t ws_size,
                              hipStream_t stream) {
  (void)in_sizes; (void)n_in; (void)out_size; (void)ws_size;
  const float* x     = (const float*)d_in[0];
  const float* Wposf = (const float*)d_in[1];
  const float* Wposd = (const float*)d_in[2];
  const float* Wc1f  = (const float*)d_in[3];
  const float* Wc1d  = (const float*)d_in[4];
  const float* Wc2f  = (const float*)d_in[5];
  const float* Wc2d  = (const float*)d_in[6];
  const float* Wtf   = (const float*)d_in[7];
  const float* Wtd   = (const float*)d_in[8];
  const float* W1f   = (const float*)d_in[9];
  const float* W1d   = (const float*)d_in[10];
  const float* W2f   = (const float*)d_in[11];
  const float* W2d   = (const float*)d_in[12];
  const float* W3    = (const float*)d_in[13];
  float* out = (float*)d_out;

  char* ws = (char*)d_ws;
  float* P          = (float*)(ws + 1310720);            // h (from knn_edge2)
  float* trans_part = (float*)(ws + 26476544);           // 512*36*4  = 73,728 B
  float* rot_part   = (float*)(ws + 26550272);           // 512*192*4 = 393,216 B

  knn_edge2_kernel<<<BATCH * NPTS / 2, 256, 0, stream>>>(x, Wposf, Wposd, P);  // x -> h
  chain_kernel<<<512, 256, 0, stream>>>(P, Wc1f, Wc1d, Wc2f, Wc2d, Wtf, Wtd,
                                        W1f, W1d, W2f, W2d, rot_part, trans_part);
  finalize_kernel<<<BATCH, 384, 0, stream>>>(rot_part, trans_part, W3, out);
}